// Round 6
// baseline (3031.741 us; speedup 1.0000x reference)
//
#include <hip/hip_runtime.h>

// GraphSAGE 2-layer, mean aggregation. N=50000, E=800000, F: 128 -> 256 -> 128.
// Layer 1: h   = relu( mean(x)@W1l + x@W1r + b1 )   (scatter raw x, then fused GEMM)
// Layer 2: out = mean(h)@W2l + h@W2r + b2
//   computed as: g2 = h@W2l; out = h@W2r + b2; out[dst] += g2[src]*rdeg[dst]
//   (linearity of mean => scatter AFTER the Wl matmul; kills the [N,256] msg2 buffer)
// NOTE: harness delivers integer inputs as int32 (NOT int64 as in the JAX ref).
constexpr int NN = 50000;
constexpr int EE = 800000;
constexpr int FI = 128;
constexpr int FH = 256;
constexpr int FO = 128;

// --- degree count: deg[dst] += 1 per edge ---
__global__ void deg_kernel(const int* __restrict__ ei, float* __restrict__ deg) {
    int e = blockIdx.x * blockDim.x + threadIdx.x;
    if (e < EE) {
        int dst = ei[EE + e];
        atomicAdd(&deg[dst], 1.0f);
    }
}

// --- deg -> 1/max(deg,1) in place ---
__global__ void rdeg_kernel(float* __restrict__ deg) {
    int n = blockIdx.x * blockDim.x + threadIdx.x;
    if (n < NN) deg[n] = 1.0f / fmaxf(deg[n], 1.0f);
}

// --- scatter-add of feature rows: msg[dst, :] += feat[src, :] ---
template<int F>
__global__ void scatter_kernel(const int* __restrict__ ei,
                               const float* __restrict__ feat,
                               float* __restrict__ msg) {
    constexpr int TPE = F / 4;
    int t = blockIdx.x * blockDim.x + threadIdx.x;
    int e = t / TPE;
    int f = (t % TPE) * 4;
    if (e >= EE) return;
    int src = ei[e];
    int dst = ei[EE + e];
    const float4 v = *reinterpret_cast<const float4*>(feat + (size_t)src * F + f);
    float* p = msg + (size_t)dst * F + f;
    atomicAdd(p + 0, v.x);
    atomicAdd(p + 1, v.y);
    atomicAdd(p + 2, v.z);
    atomicAdd(p + 3, v.w);
}

// --- scatter-add of pre-transformed rows, scaled by dst rdeg:
//     out[dst, :] += g[src, :] * rdeg[dst] ---
template<int F>
__global__ void scatter_scaled_kernel(const int* __restrict__ ei,
                                      const float* __restrict__ g,
                                      const float* __restrict__ rdeg,
                                      float* __restrict__ outp) {
    constexpr int TPE = F / 4;
    int t = blockIdx.x * blockDim.x + threadIdx.x;
    int e = t / TPE;
    int f = (t % TPE) * 4;
    if (e >= EE) return;
    int src = ei[e];
    int dst = ei[EE + e];
    const float4 v = *reinterpret_cast<const float4*>(g + (size_t)src * F + f);
    const float s = rdeg[dst];
    float* p = outp + (size_t)dst * F + f;
    atomicAdd(p + 0, v.x * s);
    atomicAdd(p + 1, v.y * s);
    atomicAdd(p + 2, v.z * s);
    atomicAdd(p + 3, v.w * s);
}

// --- fused SAGE layer: out = [relu]( (msg*rdeg) @ Wl + feat @ Wr + b ) ---
template<int Fin, int Fout, bool RELU>
__global__ __launch_bounds__(256) void sage_layer(
    const float* __restrict__ feat,   // [N, Fin]
    const float* __restrict__ msg,    // [N, Fin]
    const float* __restrict__ rdeg,   // [N]
    const float* __restrict__ Wl,     // [Fin, Fout]
    const float* __restrict__ Wr,     // [Fin, Fout]
    const float* __restrict__ bias,   // [Fout]
    float* __restrict__ outp)         // [N, Fout]
{
    constexpr int TM = 32;
    constexpr int CG = Fout / 4;    // column groups (float4 wide)
    constexpr int RG = 256 / CG;    // row groups
    constexpr int RPT = TM / RG;    // rows per thread

    __shared__ float tile[TM][Fin];

    const int row0 = blockIdx.x * TM;
    const int t = threadIdx.x;
    const int c0 = (t % CG) * 4;
    const int r0 = (t / CG) * RPT;

    float acc[RPT][4];
#pragma unroll
    for (int i = 0; i < RPT; ++i) {
        acc[i][0] = 0.f; acc[i][1] = 0.f; acc[i][2] = 0.f; acc[i][3] = 0.f;
    }

    for (int phase = 0; phase < 2; ++phase) {
        const float* __restrict__ A = (phase == 0) ? msg : feat;
        const float* __restrict__ W = (phase == 0) ? Wl : Wr;

        __syncthreads();   // previous-phase readers done before restage
        constexpr int TOT4 = TM * Fin / 4;
        for (int i = t; i < TOT4; i += 256) {
            int r = i / (Fin / 4);
            int k4 = (i % (Fin / 4)) * 4;
            int row = row0 + r;
            float4 v = make_float4(0.f, 0.f, 0.f, 0.f);
            if (row < NN) {
                v = *reinterpret_cast<const float4*>(A + (size_t)row * Fin + k4);
                if (phase == 0) {
                    float s = rdeg[row];
                    v.x *= s; v.y *= s; v.z *= s; v.w *= s;
                }
            }
            *reinterpret_cast<float4*>(&tile[r][k4]) = v;
        }
        __syncthreads();

        for (int k = 0; k < Fin; k += 4) {
            float4 w[4];
#pragma unroll
            for (int j = 0; j < 4; ++j)
                w[j] = *reinterpret_cast<const float4*>(W + (size_t)(k + j) * Fout + c0);
#pragma unroll
            for (int i = 0; i < RPT; ++i) {
                float4 a = *reinterpret_cast<const float4*>(&tile[r0 + i][k]);
                float av[4] = {a.x, a.y, a.z, a.w};
#pragma unroll
                for (int j = 0; j < 4; ++j) {
                    acc[i][0] = fmaf(av[j], w[j].x, acc[i][0]);
                    acc[i][1] = fmaf(av[j], w[j].y, acc[i][1]);
                    acc[i][2] = fmaf(av[j], w[j].z, acc[i][2]);
                    acc[i][3] = fmaf(av[j], w[j].w, acc[i][3]);
                }
            }
        }
    }

    const float4 bv = *reinterpret_cast<const float4*>(bias + c0);
#pragma unroll
    for (int i = 0; i < RPT; ++i) {
        int row = row0 + r0 + i;
        if (row < NN) {
            float4 o;
            o.x = acc[i][0] + bv.x;
            o.y = acc[i][1] + bv.y;
            o.z = acc[i][2] + bv.z;
            o.w = acc[i][3] + bv.w;
            if (RELU) {
                o.x = fmaxf(o.x, 0.f); o.y = fmaxf(o.y, 0.f);
                o.z = fmaxf(o.z, 0.f); o.w = fmaxf(o.w, 0.f);
            }
            *reinterpret_cast<float4*>(outp + (size_t)row * Fout + c0) = o;
        }
    }
}

// --- plain GEMM: out = A @ W (+ bias).  A:[N,Fin], W:[Fin,Fout] ---
template<int Fin, int Fout, bool BIAS>
__global__ __launch_bounds__(256) void gemm_kernel(
    const float* __restrict__ A,
    const float* __restrict__ W,
    const float* __restrict__ bias,
    float* __restrict__ outp)
{
    constexpr int TM = 32;
    constexpr int CG = Fout / 4;
    constexpr int RG = 256 / CG;
    constexpr int RPT = TM / RG;

    __shared__ float tile[TM][Fin];

    const int row0 = blockIdx.x * TM;
    const int t = threadIdx.x;
    const int c0 = (t % CG) * 4;
    const int r0 = (t / CG) * RPT;

    float acc[RPT][4];
#pragma unroll
    for (int i = 0; i < RPT; ++i) {
        acc[i][0] = 0.f; acc[i][1] = 0.f; acc[i][2] = 0.f; acc[i][3] = 0.f;
    }

    constexpr int TOT4 = TM * Fin / 4;
    for (int i = t; i < TOT4; i += 256) {
        int r = i / (Fin / 4);
        int k4 = (i % (Fin / 4)) * 4;
        int row = row0 + r;
        float4 v = make_float4(0.f, 0.f, 0.f, 0.f);
        if (row < NN)
            v = *reinterpret_cast<const float4*>(A + (size_t)row * Fin + k4);
        *reinterpret_cast<float4*>(&tile[r][k4]) = v;
    }
    __syncthreads();

    for (int k = 0; k < Fin; k += 4) {
        float4 w[4];
#pragma unroll
        for (int j = 0; j < 4; ++j)
            w[j] = *reinterpret_cast<const float4*>(W + (size_t)(k + j) * Fout + c0);
#pragma unroll
        for (int i = 0; i < RPT; ++i) {
            float4 a = *reinterpret_cast<const float4*>(&tile[r0 + i][k]);
            float av[4] = {a.x, a.y, a.z, a.w};
#pragma unroll
            for (int j = 0; j < 4; ++j) {
                acc[i][0] = fmaf(av[j], w[j].x, acc[i][0]);
                acc[i][1] = fmaf(av[j], w[j].y, acc[i][1]);
                acc[i][2] = fmaf(av[j], w[j].z, acc[i][2]);
                acc[i][3] = fmaf(av[j], w[j].w, acc[i][3]);
            }
        }
    }

    float4 bv = make_float4(0.f, 0.f, 0.f, 0.f);
    if (BIAS) bv = *reinterpret_cast<const float4*>(bias + c0);
#pragma unroll
    for (int i = 0; i < RPT; ++i) {
        int row = row0 + r0 + i;
        if (row < NN) {
            float4 o;
            o.x = acc[i][0] + bv.x;
            o.y = acc[i][1] + bv.y;
            o.z = acc[i][2] + bv.z;
            o.w = acc[i][3] + bv.w;
            *reinterpret_cast<float4*>(outp + (size_t)row * Fout + c0) = o;
        }
    }
}

extern "C" void kernel_launch(void* const* d_in, const int* in_sizes, int n_in,
                              void* d_out, int out_size, void* d_ws, size_t ws_size,
                              hipStream_t stream) {
    const float* x   = (const float*)d_in[0];
    const int*   ei  = (const int*)d_in[1];   // harness stages integers as int32
    const float* W1l = (const float*)d_in[2];
    const float* W1r = (const float*)d_in[3];
    const float* b1  = (const float*)d_in[4];
    const float* W2l = (const float*)d_in[5];
    const float* W2r = (const float*)d_in[6];
    const float* b2  = (const float*)d_in[7];
    float*       out = (float*)d_out;

    // workspace layout (floats): deg[N] | buf128[N*FI] (msg1, later g2) | h[N*FH]
    const size_t needed = (size_t)NN * (1 + FI + FH) * sizeof(float);  // 77.0 MB
    if (ws_size < needed) return;  // clean absmax-fail => diagnostic: ws too small

    float* ws     = (float*)d_ws;
    float* deg    = ws;
    float* buf128 = deg + NN;                 // msg1 for layer1, g2 for layer2
    float* h      = buf128 + (size_t)NN * FI;

    hipMemsetAsync(deg,    0, (size_t)NN * sizeof(float), stream);
    hipMemsetAsync(buf128, 0, (size_t)NN * FI * sizeof(float), stream);

    deg_kernel<<<(EE + 255) / 256, 256, 0, stream>>>(ei, deg);
    rdeg_kernel<<<(NN + 255) / 256, 256, 0, stream>>>(deg);

    // layer 1: scatter raw x, then fused (msg*rdeg)@W1l + x@W1r + b1, relu
    scatter_kernel<FI><<<EE * (FI / 4) / 256, 256, 0, stream>>>(ei, x, buf128);
    sage_layer<FI, FH, true><<<(NN + 31) / 32, 256, 0, stream>>>(
        x, buf128, deg, W1l, W1r, b1, h);

    // layer 2: g2 = h@W2l (reuse buf128); out = h@W2r + b2; out[dst] += g2[src]*rdeg[dst]
    gemm_kernel<FH, FO, false><<<(NN + 31) / 32, 256, 0, stream>>>(
        h, W2l, nullptr, buf128);
    gemm_kernel<FH, FO, true><<<(NN + 31) / 32, 256, 0, stream>>>(
        h, W2r, b2, out);
    scatter_scaled_kernel<FO><<<EE * (FO / 4) / 256, 256, 0, stream>>>(
        ei, buf128, deg, out);
}

// Round 7
// 600.935 us; speedup vs baseline: 5.0450x; 5.0450x over previous
//
#include <hip/hip_runtime.h>

// GraphSAGE 2-layer, mean aggregation. N=50000, E=800000, F: 128 -> 256 -> 128.
// CSR path (no feature atomics):
//   deg_i (int atomics) -> exclusive scan -> slot-assign (counting sort by dst)
//   gather1: buf128[n] = mean_{src in N(n)} x[src]           (one wave per node)
//   h = relu( buf128@W1l + x@W1r + b1 )
//   g2 = h@W2l ; out = h@W2r + b2 ; gather2: out[n] += rdeg[n]*sum g2[src]
// Fallback to the proven atomic-scatter path if ws_size < 80.6 MB.
// NOTE: harness delivers integer inputs as int32 (NOT int64 as in the JAX ref).
constexpr int NN = 50000;
constexpr int EE = 800000;
constexpr int FI = 128;
constexpr int FH = 256;
constexpr int FO = 128;

// ============================ CSR build ============================

__global__ void deg_i_kernel(const int* __restrict__ ei, int* __restrict__ deg) {
    int e = blockIdx.x * blockDim.x + threadIdx.x;
    if (e < EE) atomicAdd(&deg[ei[EE + e]], 1);
}

__global__ void rdeg_i_kernel(const int* __restrict__ deg, float* __restrict__ rdeg) {
    int n = blockIdx.x * blockDim.x + threadIdx.x;
    if (n < NN) rdeg[n] = 1.0f / fmaxf((float)deg[n], 1.0f);
}

// Single-block exclusive scan of deg[0..NN) -> rowptr. 1024 threads,
// wave-shuffle inclusive scans + 16-wave LDS combine, running carry.
__global__ __launch_bounds__(1024) void scan_kernel(const int* __restrict__ deg,
                                                    int* __restrict__ rowptr) {
    __shared__ int wsum[16];
    __shared__ int s_carry;
    const int tid = threadIdx.x;
    const int lane = tid & 63;
    const int wid = tid >> 6;
    if (tid == 0) s_carry = 0;
    __syncthreads();
    for (int base = 0; base < NN; base += 1024) {
        int i = base + tid;
        int v = (i < NN) ? deg[i] : 0;
        int s = v;
#pragma unroll
        for (int off = 1; off < 64; off <<= 1) {
            int t = __shfl_up(s, off, 64);
            if (lane >= off) s += t;
        }
        if (lane == 63) wsum[wid] = s;
        __syncthreads();
        if (wid == 0) {
            int ws = (lane < 16) ? wsum[lane] : 0;
#pragma unroll
            for (int off = 1; off < 16; off <<= 1) {
                int t = __shfl_up(ws, off, 64);
                if (lane >= off) ws += t;
            }
            if (lane < 16) wsum[lane] = ws;   // inclusive scan of wave sums
        }
        __syncthreads();
        int carry = s_carry;
        int woff = (wid > 0) ? wsum[wid - 1] : 0;
        if (i < NN) rowptr[i] = carry + woff + s - v;   // exclusive prefix
        __syncthreads();                                 // reads of s_carry/wsum done
        if (tid == 0) s_carry = carry + wsum[15];        // += chunk total
        __syncthreads();
    }
}

// slot = old rowptr[dst]; after kernel rowptr[n] = end offset of node n
// (start(n) = n==0 ? 0 : rowptr[n-1]).
__global__ void slot_kernel(const int* __restrict__ ei, int* __restrict__ rowptr,
                            int* __restrict__ csr_src) {
    int e = blockIdx.x * blockDim.x + threadIdx.x;
    if (e < EE) {
        int src = ei[e];
        int dst = ei[EE + e];
        int slot = atomicAdd(&rowptr[dst], 1);
        csr_src[slot] = src;
    }
}

// ============================ gather ============================
// One 64-lane wave per node; float2 per lane covers F=128 row (512 B/row).
// Wave-uniform neighbor loop: zero divergence, zero atomics, one writer/elem.
template<int F, bool ACCUM>
__global__ __launch_bounds__(256) void gather_kernel(
    const int* __restrict__ rowptr,
    const int* __restrict__ csr_src,
    const float* __restrict__ rdeg,
    const float* __restrict__ feat,   // [N, F] rows being gathered
    float* __restrict__ outp)         // [N, F]
{
    static_assert(F == 128, "float2 x 64 lanes covers exactly 128");
    int node = blockIdx.x * 4 + (threadIdx.x >> 6);
    if (node >= NN) return;
    int lane = threadIdx.x & 63;
    int f = lane * 2;
    int start = (node == 0) ? 0 : rowptr[node - 1];
    int end = rowptr[node];
    float2 acc = make_float2(0.f, 0.f);
    for (int j = start; j < end; ++j) {
        int src = csr_src[j];   // wave-uniform -> scalar broadcast
        float2 v = *reinterpret_cast<const float2*>(feat + (size_t)src * F + f);
        acc.x += v.x;
        acc.y += v.y;
    }
    float s = rdeg[node];
    float* p = outp + (size_t)node * F + f;
    if (ACCUM) {
        float2 o = *reinterpret_cast<float2*>(p);
        o.x += acc.x * s;
        o.y += acc.y * s;
        *reinterpret_cast<float2*>(p) = o;
    } else {
        float2 o;
        o.x = acc.x * s;
        o.y = acc.y * s;
        *reinterpret_cast<float2*>(p) = o;
    }
}

// ==================== fallback atomic-scatter path ====================

__global__ void deg_kernel(const int* __restrict__ ei, float* __restrict__ deg) {
    int e = blockIdx.x * blockDim.x + threadIdx.x;
    if (e < EE) atomicAdd(&deg[ei[EE + e]], 1.0f);
}

__global__ void rdeg_kernel(float* __restrict__ deg) {
    int n = blockIdx.x * blockDim.x + threadIdx.x;
    if (n < NN) deg[n] = 1.0f / fmaxf(deg[n], 1.0f);
}

template<int F>
__global__ void scatter_kernel(const int* __restrict__ ei,
                               const float* __restrict__ feat,
                               float* __restrict__ msg) {
    constexpr int TPE = F / 4;
    int t = blockIdx.x * blockDim.x + threadIdx.x;
    int e = t / TPE;
    int f = (t % TPE) * 4;
    if (e >= EE) return;
    int src = ei[e];
    int dst = ei[EE + e];
    const float4 v = *reinterpret_cast<const float4*>(feat + (size_t)src * F + f);
    float* p = msg + (size_t)dst * F + f;
    atomicAdd(p + 0, v.x);
    atomicAdd(p + 1, v.y);
    atomicAdd(p + 2, v.z);
    atomicAdd(p + 3, v.w);
}

template<int F>
__global__ void scatter_scaled_kernel(const int* __restrict__ ei,
                                      const float* __restrict__ g,
                                      const float* __restrict__ rdeg,
                                      float* __restrict__ outp) {
    constexpr int TPE = F / 4;
    int t = blockIdx.x * blockDim.x + threadIdx.x;
    int e = t / TPE;
    int f = (t % TPE) * 4;
    if (e >= EE) return;
    int src = ei[e];
    int dst = ei[EE + e];
    const float4 v = *reinterpret_cast<const float4*>(g + (size_t)src * F + f);
    const float s = rdeg[dst];
    float* p = outp + (size_t)dst * F + f;
    atomicAdd(p + 0, v.x * s);
    atomicAdd(p + 1, v.y * s);
    atomicAdd(p + 2, v.z * s);
    atomicAdd(p + 3, v.w * s);
}

// ============================ dense layers ============================
// out = [relu]( msg[*rdeg] @ Wl + feat @ Wr + b ). SCALEMSG=false when msg
// is already the mean (CSR gather applied rdeg).
template<int Fin, int Fout, bool RELU, bool SCALEMSG>
__global__ __launch_bounds__(256) void sage_layer(
    const float* __restrict__ feat,
    const float* __restrict__ msg,
    const float* __restrict__ rdeg,
    const float* __restrict__ Wl,
    const float* __restrict__ Wr,
    const float* __restrict__ bias,
    float* __restrict__ outp)
{
    constexpr int TM = 32;
    constexpr int CG = Fout / 4;
    constexpr int RG = 256 / CG;
    constexpr int RPT = TM / RG;

    __shared__ float tile[TM][Fin];

    const int row0 = blockIdx.x * TM;
    const int t = threadIdx.x;
    const int c0 = (t % CG) * 4;
    const int r0 = (t / CG) * RPT;

    float acc[RPT][4];
#pragma unroll
    for (int i = 0; i < RPT; ++i) {
        acc[i][0] = 0.f; acc[i][1] = 0.f; acc[i][2] = 0.f; acc[i][3] = 0.f;
    }

    for (int phase = 0; phase < 2; ++phase) {
        const float* __restrict__ A = (phase == 0) ? msg : feat;
        const float* __restrict__ W = (phase == 0) ? Wl : Wr;

        __syncthreads();
        constexpr int TOT4 = TM * Fin / 4;
        for (int i = t; i < TOT4; i += 256) {
            int r = i / (Fin / 4);
            int k4 = (i % (Fin / 4)) * 4;
            int row = row0 + r;
            float4 v = make_float4(0.f, 0.f, 0.f, 0.f);
            if (row < NN) {
                v = *reinterpret_cast<const float4*>(A + (size_t)row * Fin + k4);
                if (SCALEMSG && phase == 0) {
                    float s = rdeg[row];
                    v.x *= s; v.y *= s; v.z *= s; v.w *= s;
                }
            }
            *reinterpret_cast<float4*>(&tile[r][k4]) = v;
        }
        __syncthreads();

        for (int k = 0; k < Fin; k += 4) {
            float4 w[4];
#pragma unroll
            for (int j = 0; j < 4; ++j)
                w[j] = *reinterpret_cast<const float4*>(W + (size_t)(k + j) * Fout + c0);
#pragma unroll
            for (int i = 0; i < RPT; ++i) {
                float4 a = *reinterpret_cast<const float4*>(&tile[r0 + i][k]);
                float av[4] = {a.x, a.y, a.z, a.w};
#pragma unroll
                for (int j = 0; j < 4; ++j) {
                    acc[i][0] = fmaf(av[j], w[j].x, acc[i][0]);
                    acc[i][1] = fmaf(av[j], w[j].y, acc[i][1]);
                    acc[i][2] = fmaf(av[j], w[j].z, acc[i][2]);
                    acc[i][3] = fmaf(av[j], w[j].w, acc[i][3]);
                }
            }
        }
    }

    const float4 bv = *reinterpret_cast<const float4*>(bias + c0);
#pragma unroll
    for (int i = 0; i < RPT; ++i) {
        int row = row0 + r0 + i;
        if (row < NN) {
            float4 o;
            o.x = acc[i][0] + bv.x;
            o.y = acc[i][1] + bv.y;
            o.z = acc[i][2] + bv.z;
            o.w = acc[i][3] + bv.w;
            if (RELU) {
                o.x = fmaxf(o.x, 0.f); o.y = fmaxf(o.y, 0.f);
                o.z = fmaxf(o.z, 0.f); o.w = fmaxf(o.w, 0.f);
            }
            *reinterpret_cast<float4*>(outp + (size_t)row * Fout + c0) = o;
        }
    }
}

template<int Fin, int Fout, bool BIAS>
__global__ __launch_bounds__(256) void gemm_kernel(
    const float* __restrict__ A,
    const float* __restrict__ W,
    const float* __restrict__ bias,
    float* __restrict__ outp)
{
    constexpr int TM = 32;
    constexpr int CG = Fout / 4;
    constexpr int RG = 256 / CG;
    constexpr int RPT = TM / RG;

    __shared__ float tile[TM][Fin];

    const int row0 = blockIdx.x * TM;
    const int t = threadIdx.x;
    const int c0 = (t % CG) * 4;
    const int r0 = (t / CG) * RPT;

    float acc[RPT][4];
#pragma unroll
    for (int i = 0; i < RPT; ++i) {
        acc[i][0] = 0.f; acc[i][1] = 0.f; acc[i][2] = 0.f; acc[i][3] = 0.f;
    }

    constexpr int TOT4 = TM * Fin / 4;
    for (int i = t; i < TOT4; i += 256) {
        int r = i / (Fin / 4);
        int k4 = (i % (Fin / 4)) * 4;
        int row = row0 + r;
        float4 v = make_float4(0.f, 0.f, 0.f, 0.f);
        if (row < NN)
            v = *reinterpret_cast<const float4*>(A + (size_t)row * Fin + k4);
        *reinterpret_cast<float4*>(&tile[r][k4]) = v;
    }
    __syncthreads();

    for (int k = 0; k < Fin; k += 4) {
        float4 w[4];
#pragma unroll
        for (int j = 0; j < 4; ++j)
            w[j] = *reinterpret_cast<const float4*>(W + (size_t)(k + j) * Fout + c0);
#pragma unroll
        for (int i = 0; i < RPT; ++i) {
            float4 a = *reinterpret_cast<const float4*>(&tile[r0 + i][k]);
            float av[4] = {a.x, a.y, a.z, a.w};
#pragma unroll
            for (int j = 0; j < 4; ++j) {
                acc[i][0] = fmaf(av[j], w[j].x, acc[i][0]);
                acc[i][1] = fmaf(av[j], w[j].y, acc[i][1]);
                acc[i][2] = fmaf(av[j], w[j].z, acc[i][2]);
                acc[i][3] = fmaf(av[j], w[j].w, acc[i][3]);
            }
        }
    }

    float4 bv = make_float4(0.f, 0.f, 0.f, 0.f);
    if (BIAS) bv = *reinterpret_cast<const float4*>(bias + c0);
#pragma unroll
    for (int i = 0; i < RPT; ++i) {
        int row = row0 + r0 + i;
        if (row < NN) {
            float4 o;
            o.x = acc[i][0] + bv.x;
            o.y = acc[i][1] + bv.y;
            o.z = acc[i][2] + bv.z;
            o.w = acc[i][3] + bv.w;
            *reinterpret_cast<float4*>(outp + (size_t)row * Fout + c0) = o;
        }
    }
}

extern "C" void kernel_launch(void* const* d_in, const int* in_sizes, int n_in,
                              void* d_out, int out_size, void* d_ws, size_t ws_size,
                              hipStream_t stream) {
    const float* x   = (const float*)d_in[0];
    const int*   ei  = (const int*)d_in[1];   // harness stages integers as int32
    const float* W1l = (const float*)d_in[2];
    const float* W1r = (const float*)d_in[3];
    const float* b1  = (const float*)d_in[4];
    const float* W2l = (const float*)d_in[5];
    const float* W2r = (const float*)d_in[6];
    const float* b2  = (const float*)d_in[7];
    float*       out = (float*)d_out;

    // CSR layout (4B units): deg_i[N] | rowptr[N] | csr_src[E] | rdeg[N]
    //                        | buf128[N*128] | h[N*256]          = 80.6 MB
    const size_t needed_csr    = ((size_t)NN * (1 + 1 + 1 + FI + FH) + EE) * 4;
    const size_t needed_atomic = (size_t)NN * (1 + FI + FH) * 4;   // 77.0 MB

    if (ws_size >= needed_csr) {
        int*   deg_i   = (int*)d_ws;
        int*   rowptr  = deg_i + NN;
        int*   csr_src = rowptr + NN;
        float* rdeg    = (float*)(csr_src + EE);
        float* buf128  = rdeg + NN;                 // mean1, later g2
        float* h       = buf128 + (size_t)NN * FI;

        hipMemsetAsync(deg_i, 0, (size_t)NN * sizeof(int), stream);
        deg_i_kernel<<<(EE + 255) / 256, 256, 0, stream>>>(ei, deg_i);
        scan_kernel<<<1, 1024, 0, stream>>>(deg_i, rowptr);
        rdeg_i_kernel<<<(NN + 255) / 256, 256, 0, stream>>>(deg_i, rdeg);
        slot_kernel<<<(EE + 255) / 256, 256, 0, stream>>>(ei, rowptr, csr_src);

        // layer 1: buf128 = mean(x); h = relu(buf128@W1l + x@W1r + b1)
        gather_kernel<FI, false><<<(NN + 3) / 4, 256, 0, stream>>>(
            rowptr, csr_src, rdeg, x, buf128);
        sage_layer<FI, FH, true, false><<<(NN + 31) / 32, 256, 0, stream>>>(
            x, buf128, rdeg, W1l, W1r, b1, h);

        // layer 2: g2 = h@W2l; out = h@W2r + b2; out[n] += rdeg[n]*sum g2[src]
        gemm_kernel<FH, FO, false><<<(NN + 31) / 32, 256, 0, stream>>>(
            h, W2l, nullptr, buf128);
        gemm_kernel<FH, FO, true><<<(NN + 31) / 32, 256, 0, stream>>>(
            h, W2r, b2, out);
        gather_kernel<FO, true><<<(NN + 3) / 4, 256, 0, stream>>>(
            rowptr, csr_src, rdeg, buf128, out);
        return;
    }

    if (ws_size < needed_atomic) return;  // clean fail => ws too small even for fallback

    // -------- fallback: proven atomic-scatter path (R6: 3032 us) --------
    float* ws     = (float*)d_ws;
    float* deg    = ws;
    float* buf128 = deg + NN;
    float* h      = buf128 + (size_t)NN * FI;

    hipMemsetAsync(deg,    0, (size_t)NN * sizeof(float), stream);
    hipMemsetAsync(buf128, 0, (size_t)NN * FI * sizeof(float), stream);

    deg_kernel<<<(EE + 255) / 256, 256, 0, stream>>>(ei, deg);
    rdeg_kernel<<<(NN + 255) / 256, 256, 0, stream>>>(deg);

    scatter_kernel<FI><<<EE * (FI / 4) / 256, 256, 0, stream>>>(ei, x, buf128);
    sage_layer<FI, FH, true, true><<<(NN + 31) / 32, 256, 0, stream>>>(
        x, buf128, deg, W1l, W1r, b1, h);

    gemm_kernel<FH, FO, false><<<(NN + 31) / 32, 256, 0, stream>>>(
        h, W2l, nullptr, buf128);
    gemm_kernel<FH, FO, true><<<(NN + 31) / 32, 256, 0, stream>>>(
        h, W2r, b2, out);
    scatter_scaled_kernel<FO><<<EE * (FO / 4) / 256, 256, 0, stream>>>(
        ei, buf128, deg, out);
}

// Round 8
// 494.831 us; speedup vs baseline: 6.1268x; 1.2144x over previous
//
#include <hip/hip_runtime.h>

// GraphSAGE 2-layer, mean agg. N=50000, E=800000, F: 128 -> 256 -> 128.
// CSR build -> gather1(mean(x), bf16) -> MFMA L1 -> MFMA L2 -> gather2(accum).
// Both layers cast to ONE bf16 GEMM shape: [N x 256] @ [256 x 256] (B^T form):
//   L1: A1=[mean(x)|x] (K-concat),  B1T=[W1l;W1r]^T, epi: +b1, relu -> h bf16
//   L2: A2=h,  B2T=[W2r|W2l] (N-concat), epi: cols<128 -> out=+b2 (f32),
//                                              cols>=128 -> g2 (f32, reuses A1 buf)
//   out[n] += rdeg[n] * sum_{src} g2[src]   (linearity of mean)
// NOTE: harness delivers integer inputs as int32 (NOT int64 as in the JAX ref).
constexpr int NN = 50000;
constexpr int EE = 800000;
constexpr int FI = 128;
constexpr int FH = 256;
constexpr int FO = 128;

typedef __attribute__((ext_vector_type(4))) float f32x4;
typedef __attribute__((ext_vector_type(8))) short bf16x8;

__device__ inline unsigned short f2bf(float f) {   // RNE f32 -> bf16
    union { float f; unsigned u; } v; v.f = f;
    unsigned r = v.u + 0x7FFFu + ((v.u >> 16) & 1u);
    return (unsigned short)(r >> 16);
}

// ============================ CSR build (R7-proven) ============================

__global__ void deg_i_kernel(const int* __restrict__ ei, int* __restrict__ deg) {
    int e = blockIdx.x * blockDim.x + threadIdx.x;
    if (e < EE) atomicAdd(&deg[ei[EE + e]], 1);
}

__global__ void rdeg_i_kernel(const int* __restrict__ deg, float* __restrict__ rdeg) {
    int n = blockIdx.x * blockDim.x + threadIdx.x;
    if (n < NN) rdeg[n] = 1.0f / fmaxf((float)deg[n], 1.0f);
}

__global__ __launch_bounds__(1024) void scan_kernel(const int* __restrict__ deg,
                                                    int* __restrict__ rowptr) {
    __shared__ int wsum[16];
    __shared__ int s_carry;
    const int tid = threadIdx.x;
    const int lane = tid & 63;
    const int wid = tid >> 6;
    if (tid == 0) s_carry = 0;
    __syncthreads();
    for (int base = 0; base < NN; base += 1024) {
        int i = base + tid;
        int v = (i < NN) ? deg[i] : 0;
        int s = v;
#pragma unroll
        for (int off = 1; off < 64; off <<= 1) {
            int t = __shfl_up(s, off, 64);
            if (lane >= off) s += t;
        }
        if (lane == 63) wsum[wid] = s;
        __syncthreads();
        if (wid == 0) {
            int ws = (lane < 16) ? wsum[lane] : 0;
#pragma unroll
            for (int off = 1; off < 16; off <<= 1) {
                int t = __shfl_up(ws, off, 64);
                if (lane >= off) ws += t;
            }
            if (lane < 16) wsum[lane] = ws;
        }
        __syncthreads();
        int carry = s_carry;
        int woff = (wid > 0) ? wsum[wid - 1] : 0;
        if (i < NN) rowptr[i] = carry + woff + s - v;
        __syncthreads();
        if (tid == 0) s_carry = carry + wsum[15];
        __syncthreads();
    }
}

__global__ void slot_kernel(const int* __restrict__ ei, int* __restrict__ rowptr,
                            int* __restrict__ csr_src) {
    int e = blockIdx.x * blockDim.x + threadIdx.x;
    if (e < EE) {
        int src = ei[e];
        int dst = ei[EE + e];
        int slot = atomicAdd(&rowptr[dst], 1);
        csr_src[slot] = src;
    }
}

// ============================ gathers ============================
// One 64-lane wave per node; float2/lane = 128 cols. Wave-uniform loop.

// mean(x) -> bf16 into A1 cols [0,128); A1 row stride 256 bf16.
__global__ __launch_bounds__(256) void gather_mean_bf16(
    const int* __restrict__ rowptr, const int* __restrict__ csr_src,
    const float* __restrict__ rdeg, const float* __restrict__ feat,  // [N][128] f32
    unsigned short* __restrict__ A1)                                 // [N][256] bf16
{
    int node = blockIdx.x * 4 + (threadIdx.x >> 6);
    if (node >= NN) return;
    int lane = threadIdx.x & 63;
    int f = lane * 2;
    int start = (node == 0) ? 0 : rowptr[node - 1];
    int end = rowptr[node];
    float2 acc = make_float2(0.f, 0.f);
    for (int j = start; j < end; ++j) {
        int src = csr_src[j];
        float2 v = *reinterpret_cast<const float2*>(feat + (size_t)src * FI + f);
        acc.x += v.x;
        acc.y += v.y;
    }
    float s = rdeg[node];
    ushort2 o;
    o.x = f2bf(acc.x * s);
    o.y = f2bf(acc.y * s);
    *reinterpret_cast<ushort2*>(A1 + (size_t)node * 256 + f) = o;
}

// out[node] += rdeg[node] * sum g2[src]   (f32)
__global__ __launch_bounds__(256) void gather_accum_f32(
    const int* __restrict__ rowptr, const int* __restrict__ csr_src,
    const float* __restrict__ rdeg, const float* __restrict__ g2,   // [N][128] f32
    float* __restrict__ outp)                                       // [N][128] f32
{
    int node = blockIdx.x * 4 + (threadIdx.x >> 6);
    if (node >= NN) return;
    int lane = threadIdx.x & 63;
    int f = lane * 2;
    int start = (node == 0) ? 0 : rowptr[node - 1];
    int end = rowptr[node];
    float2 acc = make_float2(0.f, 0.f);
    for (int j = start; j < end; ++j) {
        int src = csr_src[j];
        float2 v = *reinterpret_cast<const float2*>(g2 + (size_t)src * FO + f);
        acc.x += v.x;
        acc.y += v.y;
    }
    float s = rdeg[node];
    float* p = outp + (size_t)node * FO + f;
    float2 o = *reinterpret_cast<float2*>(p);
    o.x += acc.x * s;
    o.y += acc.y * s;
    *reinterpret_cast<float2*>(p) = o;
}

// ============================ prep kernels ============================

// x f32 [N][128] -> bf16 into A1 cols [128,256)
__global__ void cast_x_kernel(const float* __restrict__ x,
                              unsigned short* __restrict__ A1) {
    int i = blockIdx.x * blockDim.x + threadIdx.x;    // N*32 float4s
    if (i >= NN * 32) return;
    int n = i >> 5;
    int c4 = (i & 31) * 4;
    float4 v = *reinterpret_cast<const float4*>(x + (size_t)n * FI + c4);
    ushort4 o;
    o.x = f2bf(v.x); o.y = f2bf(v.y); o.z = f2bf(v.z); o.w = f2bf(v.w);
    *reinterpret_cast<ushort4*>(A1 + (size_t)n * 256 + 128 + c4) = o;
}

// B1T[n][k] = k<128 ? W1l[k][n] : W1r[k-128][n]     (W1* are [128][256])
// B2T[n][k] = n<128 ? W2r[k][n] : W2l[k][n-128]     (W2* are [256][128])
__global__ void prep_weights(const float* __restrict__ W1l, const float* __restrict__ W1r,
                             const float* __restrict__ W2l, const float* __restrict__ W2r,
                             unsigned short* __restrict__ B1T,
                             unsigned short* __restrict__ B2T) {
    int i = blockIdx.x * blockDim.x + threadIdx.x;
    if (i >= 256 * 256) return;
    int n = i >> 8, k = i & 255;
    float v1 = (k < 128) ? W1l[(size_t)k * 256 + n] : W1r[(size_t)(k - 128) * 256 + n];
    B1T[(size_t)n * 256 + k] = f2bf(v1);
    float v2 = (n < 128) ? W2r[(size_t)k * 128 + n] : W2l[(size_t)k * 128 + (n - 128)];
    B2T[(size_t)n * 256 + k] = f2bf(v2);
}

// ============================ MFMA GEMM ============================
// C[N x 256] = A[N x 256] @ B^T[256 x 256], bf16 in, f32 acc.
// 256 thr / 4 waves; BM=64 (wave w owns rows 16w..16w+15); BK=64 chunks.
// Fragment layout (m89/m92-verified): A row=lane&15, k=(lane>>4)*8+e (contig 8);
// B^T n=lane&15, same k; D col=lane&15, row=(lane>>4)*4+j.
// MODE 0 (L1): +bias[256], relu, store bf16 h[N][256].
// MODE 1 (L2): col<128 -> out_f0 = acc + bias[col]; col>=128 -> out_f1 = acc.
constexpr int GPAD = 80;   // bf16 per LDS row (64 + 16 pad; keeps 16B align, 4-way max)

template<int MODE>
__global__ __launch_bounds__(256) void mfma_gemm(
    const unsigned short* __restrict__ A,    // [N][256] bf16
    const unsigned short* __restrict__ BT,   // [256][256] bf16
    const float* __restrict__ bias,
    unsigned short* __restrict__ out_bf,     // MODE 0
    float* __restrict__ out_f0,              // MODE 1
    float* __restrict__ out_f1)              // MODE 1
{
    __shared__ unsigned short Al[64][GPAD];    // 10.0 KB
    __shared__ unsigned short Bl[256][GPAD];   // 40.0 KB

    const int t = threadIdx.x;
    const int wid = t >> 6;
    const int lane = t & 63;
    const int l15 = lane & 15;
    const int lhi = lane >> 4;          // 0..3
    const int row0 = blockIdx.x * 64;

    f32x4 acc[16];
#pragma unroll
    for (int n = 0; n < 16; ++n) acc[n] = f32x4{0.f, 0.f, 0.f, 0.f};

    for (int kc = 0; kc < 256; kc += 64) {
        __syncthreads();   // previous chunk's readers done
        // stage A chunk: 64 rows x 64 bf16 (2 x 16B per thread)
#pragma unroll
        for (int i = 0; i < 2; ++i) {
            int idx = t + i * 256;
            int r = idx >> 3;
            int c = (idx & 7) * 8;
            int rr = row0 + r;
            if (rr >= NN) rr = NN - 1;                       // clamp (rows unused)
            *reinterpret_cast<uint4*>(&Al[r][c]) =
                *reinterpret_cast<const uint4*>(A + (size_t)rr * 256 + kc + c);
        }
        // stage BT chunk: 256 rows x 64 bf16 (8 x 16B per thread)
#pragma unroll
        for (int i = 0; i < 8; ++i) {
            int idx = t + i * 256;
            int r = idx >> 3;
            int c = (idx & 7) * 8;
            *reinterpret_cast<uint4*>(&Bl[r][c]) =
                *reinterpret_cast<const uint4*>(BT + (size_t)r * 256 + kc + c);
        }
        __syncthreads();
#pragma unroll
        for (int ks = 0; ks < 64; ks += 32) {
            bf16x8 a = *reinterpret_cast<const bf16x8*>(&Al[wid * 16 + l15][ks + lhi * 8]);
#pragma unroll
            for (int n = 0; n < 16; ++n) {
                bf16x8 b = *reinterpret_cast<const bf16x8*>(&Bl[n * 16 + l15][ks + lhi * 8]);
                acc[n] = __builtin_amdgcn_mfma_f32_16x16x32_bf16(a, b, acc[n], 0, 0, 0);
            }
        }
    }

#pragma unroll
    for (int n = 0; n < 16; ++n) {
        int col = n * 16 + l15;
#pragma unroll
        for (int j = 0; j < 4; ++j) {
            int row = row0 + wid * 16 + lhi * 4 + j;
            if (row < NN) {
                float v = acc[n][j];
                if (MODE == 0) {
                    v += bias[col];
                    v = fmaxf(v, 0.f);
                    out_bf[(size_t)row * 256 + col] = f2bf(v);
                } else {
                    if (col < 128) out_f0[(size_t)row * 128 + col] = v + bias[col];
                    else           out_f1[(size_t)row * 128 + (col - 128)] = v;
                }
            }
        }
    }
}

// ============================ launch ============================

extern "C" void kernel_launch(void* const* d_in, const int* in_sizes, int n_in,
                              void* d_out, int out_size, void* d_ws, size_t ws_size,
                              hipStream_t stream) {
    const float* x   = (const float*)d_in[0];
    const int*   ei  = (const int*)d_in[1];   // harness stages integers as int32
    const float* W1l = (const float*)d_in[2];
    const float* W1r = (const float*)d_in[3];
    const float* b1  = (const float*)d_in[4];
    const float* W2l = (const float*)d_in[5];
    const float* W2r = (const float*)d_in[6];
    const float* b2  = (const float*)d_in[7];
    float*       out = (float*)d_out;

    // ws layout (4B units):
    //   deg_i[N] | rowptr[N] | csr_src[E] | rdeg[N]
    //   | A1 (N*256 bf16 = N*128 units; g2 f32 [N][128] reuses this after L1)
    //   | h  (N*256 bf16 = N*128 units)
    //   | B1T (256*256 bf16 = 32768 units) | B2T (32768 units)
    const size_t needed = ((size_t)NN * 3 + EE + (size_t)NN * 128 * 2 + 65536) * 4; // 55.3 MB
    if (ws_size < needed) return;   // clean fail => ws smaller than R7-proven bound

    int*            deg_i   = (int*)d_ws;
    int*            rowptr  = deg_i + NN;
    int*            csr_src = rowptr + NN;
    float*          rdeg    = (float*)(csr_src + EE);
    unsigned short* A1      = (unsigned short*)(rdeg + NN);     // [N][256] bf16
    float*          g2      = (float*)A1;                       // [N][128] f32 (after L1)
    unsigned short* h       = A1 + (size_t)NN * 256;            // [N][256] bf16
    unsigned short* B1T     = h + (size_t)NN * 256;
    unsigned short* B2T     = B1T + 256 * 256;

    // CSR build + weight prep (independent of each other)
    hipMemsetAsync(deg_i, 0, (size_t)NN * sizeof(int), stream);
    prep_weights<<<256, 256, 0, stream>>>(W1l, W1r, W2l, W2r, B1T, B2T);
    cast_x_kernel<<<(NN * 32 + 255) / 256, 256, 0, stream>>>(x, A1);
    deg_i_kernel<<<(EE + 255) / 256, 256, 0, stream>>>(ei, deg_i);
    scan_kernel<<<1, 1024, 0, stream>>>(deg_i, rowptr);
    rdeg_i_kernel<<<(NN + 255) / 256, 256, 0, stream>>>(deg_i, rdeg);
    slot_kernel<<<(EE + 255) / 256, 256, 0, stream>>>(ei, rowptr, csr_src);

    // layer 1: A1[:,0:128] = mean(x) (bf16); h = relu(A1 @ B1T^T + b1) (bf16)
    gather_mean_bf16<<<(NN + 3) / 4, 256, 0, stream>>>(rowptr, csr_src, rdeg, x, A1);
    mfma_gemm<0><<<(NN + 63) / 64, 256, 0, stream>>>(A1, B1T, b1, h, nullptr, nullptr);

    // layer 2: out = h@W2r + b2 (f32), g2 = h@W2l (f32, overwrites dead A1)
    mfma_gemm<1><<<(NN + 63) / 64, 256, 0, stream>>>(h, B2T, b2, nullptr, out, g2);

    // out[n] += rdeg[n] * sum g2[src]
    gather_accum_f32<<<(NN + 3) / 4, 256, 0, stream>>>(rowptr, csr_src, rdeg, g2, out);
}

// Round 9
// 388.463 us; speedup vs baseline: 7.8045x; 1.2738x over previous
//
#include <hip/hip_runtime.h>

// GraphSAGE 2-layer, mean agg. N=50000, E=800000, F: 128 -> 256 -> 128.
// CSR build -> gather1(mean of bf16 x) -> MFMA L1 -> MFMA L2 -> gather2(bf16 g2, accum).
//   L1: A1=[mean(x)|x] bf16 K-concat,  B1T=[W1l;W1r]^T, epi: +b1, relu -> h bf16
//   L2: A2=h, B2T=[W2r|W2l] N-concat, epi: cols<128 -> out=+b2 (f32),
//                                          cols>=128 -> g2 bf16 (reuses A1 buf)
//   out[n] += rdeg[n] * sum_{src} g2[src]   (linearity of mean)
// NOTE: harness delivers integer inputs as int32 (NOT int64 as in the JAX ref).
constexpr int NN = 50000;
constexpr int EE = 800000;
constexpr int FI = 128;
constexpr int FO = 128;

typedef __attribute__((ext_vector_type(4))) float f32x4;
typedef __attribute__((ext_vector_type(8))) short bf16x8;

__device__ inline unsigned short f2bf(float f) {   // RNE f32 -> bf16
    union { float f; unsigned u; } v; v.f = f;
    unsigned r = v.u + 0x7FFFu + ((v.u >> 16) & 1u);
    return (unsigned short)(r >> 16);
}
__device__ inline float bf2f(unsigned short u) {
    union { unsigned u; float f; } v; v.u = ((unsigned)u) << 16; return v.f;
}

// ============================ CSR build ============================

__global__ void deg_i_kernel(const int* __restrict__ ei, int* __restrict__ deg) {
    int e = blockIdx.x * blockDim.x + threadIdx.x;
    if (e < EE) atomicAdd(&deg[ei[EE + e]], 1);
}

__global__ void rdeg_i_kernel(const int* __restrict__ deg, float* __restrict__ rdeg) {
    int n = blockIdx.x * blockDim.x + threadIdx.x;
    if (n < NN) rdeg[n] = 1.0f / fmaxf((float)deg[n], 1.0f);
}

// 3-phase exclusive scan of deg -> rowptr (multi-block, ~8 us total).
constexpr int SCAN_NBLK = (NN + 1023) / 1024;   // 49

__global__ __launch_bounds__(1024) void scan_phase1(const int* __restrict__ deg,
                                                    int* __restrict__ rowptr,
                                                    int* __restrict__ bsum) {
    __shared__ int wsum[16];
    const int tid = threadIdx.x;
    const int lane = tid & 63;
    const int wid = tid >> 6;
    int i = blockIdx.x * 1024 + tid;
    int v = (i < NN) ? deg[i] : 0;
    int s = v;
#pragma unroll
    for (int off = 1; off < 64; off <<= 1) {
        int t = __shfl_up(s, off, 64);
        if (lane >= off) s += t;
    }
    if (lane == 63) wsum[wid] = s;
    __syncthreads();
    if (wid == 0) {
        int ws = (lane < 16) ? wsum[lane] : 0;
#pragma unroll
        for (int off = 1; off < 16; off <<= 1) {
            int t = __shfl_up(ws, off, 64);
            if (lane >= off) ws += t;
        }
        if (lane < 16) wsum[lane] = ws;
    }
    __syncthreads();
    int woff = (wid > 0) ? wsum[wid - 1] : 0;
    if (i < NN) rowptr[i] = woff + s - v;           // exclusive within block
    if (tid == 0) bsum[blockIdx.x] = wsum[15];      // block total
}

__global__ void scan_phase2(int* __restrict__ bsum) {   // one wave, NBLK<=64
    int lane = threadIdx.x;
    int v = (lane < SCAN_NBLK) ? bsum[lane] : 0;
    int s = v;
#pragma unroll
    for (int off = 1; off < 64; off <<= 1) {
        int t = __shfl_up(s, off, 64);
        if (lane >= off) s += t;
    }
    if (lane < SCAN_NBLK) bsum[lane] = s - v;       // exclusive block offsets
}

__global__ void scan_phase3(int* __restrict__ rowptr, const int* __restrict__ bsum) {
    int i = blockIdx.x * blockDim.x + threadIdx.x;
    if (i < NN) rowptr[i] += bsum[i >> 10];
}

// slot = old rowptr[dst]; after kernel rowptr[n] = end offset of node n.
__global__ void slot_kernel(const int* __restrict__ ei, int* __restrict__ rowptr,
                            int* __restrict__ csr_src) {
    int e = blockIdx.x * blockDim.x + threadIdx.x;
    if (e < EE) {
        int src = ei[e];
        int dst = ei[EE + e];
        int slot = atomicAdd(&rowptr[dst], 1);
        csr_src[slot] = src;
    }
}

// ============================ gathers ============================
// One 64-lane wave per node, bf16 rows (256 B), unroll-2 latency chains.

// mean over neighbors of bf16 x (A1 cols [128,256)) -> bf16 A1 cols [0,128).
__global__ __launch_bounds__(256) void gather_mean_bf16(
    const int* __restrict__ rowptr, const int* __restrict__ csr_src,
    const float* __restrict__ rdeg,
    unsigned short* __restrict__ A1)        // [N][256] bf16; reads col128+, writes col<128
{
    int node = blockIdx.x * 4 + (threadIdx.x >> 6);
    if (node >= NN) return;
    int lane = threadIdx.x & 63;
    int f = lane * 2;
    int start = (node == 0) ? 0 : rowptr[node - 1];
    int end = rowptr[node];
    float ax0 = 0.f, ay0 = 0.f, ax1 = 0.f, ay1 = 0.f;
    int j = start;
    for (; j + 1 < end; j += 2) {
        int s0 = csr_src[j];
        int s1 = csr_src[j + 1];
        ushort2 v0 = *reinterpret_cast<const ushort2*>(A1 + (size_t)s0 * 256 + 128 + f);
        ushort2 v1 = *reinterpret_cast<const ushort2*>(A1 + (size_t)s1 * 256 + 128 + f);
        ax0 += bf2f(v0.x); ay0 += bf2f(v0.y);
        ax1 += bf2f(v1.x); ay1 += bf2f(v1.y);
    }
    if (j < end) {
        int s0 = csr_src[j];
        ushort2 v0 = *reinterpret_cast<const ushort2*>(A1 + (size_t)s0 * 256 + 128 + f);
        ax0 += bf2f(v0.x); ay0 += bf2f(v0.y);
    }
    float s = rdeg[node];
    ushort2 o;
    o.x = f2bf((ax0 + ax1) * s);
    o.y = f2bf((ay0 + ay1) * s);
    *reinterpret_cast<ushort2*>(A1 + (size_t)node * 256 + f) = o;
}

// out[node] += rdeg[node] * sum g2b[src]   (g2b bf16 [N][128], out f32)
__global__ __launch_bounds__(256) void gather_accum_f32(
    const int* __restrict__ rowptr, const int* __restrict__ csr_src,
    const float* __restrict__ rdeg, const unsigned short* __restrict__ g2b,
    float* __restrict__ outp)
{
    int node = blockIdx.x * 4 + (threadIdx.x >> 6);
    if (node >= NN) return;
    int lane = threadIdx.x & 63;
    int f = lane * 2;
    int start = (node == 0) ? 0 : rowptr[node - 1];
    int end = rowptr[node];
    float ax0 = 0.f, ay0 = 0.f, ax1 = 0.f, ay1 = 0.f;
    int j = start;
    for (; j + 1 < end; j += 2) {
        int s0 = csr_src[j];
        int s1 = csr_src[j + 1];
        ushort2 v0 = *reinterpret_cast<const ushort2*>(g2b + (size_t)s0 * 128 + f);
        ushort2 v1 = *reinterpret_cast<const ushort2*>(g2b + (size_t)s1 * 128 + f);
        ax0 += bf2f(v0.x); ay0 += bf2f(v0.y);
        ax1 += bf2f(v1.x); ay1 += bf2f(v1.y);
    }
    if (j < end) {
        int s0 = csr_src[j];
        ushort2 v0 = *reinterpret_cast<const ushort2*>(g2b + (size_t)s0 * 128 + f);
        ax0 += bf2f(v0.x); ay0 += bf2f(v0.y);
    }
    float s = rdeg[node];
    float* p = outp + (size_t)node * FO + f;
    float2 o = *reinterpret_cast<float2*>(p);
    o.x += (ax0 + ax1) * s;
    o.y += (ay0 + ay1) * s;
    *reinterpret_cast<float2*>(p) = o;
}

// ============================ prep kernels ============================

__global__ void cast_x_kernel(const float* __restrict__ x,
                              unsigned short* __restrict__ A1) {
    int i = blockIdx.x * blockDim.x + threadIdx.x;    // N*32 float4s
    if (i >= NN * 32) return;
    int n = i >> 5;
    int c4 = (i & 31) * 4;
    float4 v = *reinterpret_cast<const float4*>(x + (size_t)n * FI + c4);
    ushort4 o;
    o.x = f2bf(v.x); o.y = f2bf(v.y); o.z = f2bf(v.z); o.w = f2bf(v.w);
    *reinterpret_cast<ushort4*>(A1 + (size_t)n * 256 + 128 + c4) = o;
}

// B1T[n][k] = k<128 ? W1l[k][n] : W1r[k-128][n]     (W1* are [128][256])
// B2T[n][k] = n<128 ? W2r[k][n] : W2l[k][n-128]     (W2* are [256][128])
__global__ void prep_weights(const float* __restrict__ W1l, const float* __restrict__ W1r,
                             const float* __restrict__ W2l, const float* __restrict__ W2r,
                             unsigned short* __restrict__ B1T,
                             unsigned short* __restrict__ B2T) {
    int i = blockIdx.x * blockDim.x + threadIdx.x;
    if (i >= 256 * 256) return;
    int n = i >> 8, k = i & 255;
    float v1 = (k < 128) ? W1l[(size_t)k * 256 + n] : W1r[(size_t)(k - 128) * 256 + n];
    B1T[(size_t)n * 256 + k] = f2bf(v1);
    float v2 = (n < 128) ? W2r[(size_t)k * 128 + n] : W2l[(size_t)k * 128 + (n - 128)];
    B2T[(size_t)n * 256 + k] = f2bf(v2);
}

// ============================ MFMA GEMM ============================
// C[N x 256] = A[N x 256] @ B^T[256 x 256], bf16 in, f32 acc. (R8-proven)
// MODE 0 (L1): +bias[256], relu, store bf16 h.   MODE 1 (L2): col<128 ->
// out_f0 = acc + bias (f32); col>=128 -> g2b = bf16(acc).
constexpr int GPAD = 80;

template<int MODE>
__global__ __launch_bounds__(256) void mfma_gemm(
    const unsigned short* __restrict__ A,    // [N][256] bf16
    const unsigned short* __restrict__ BT,   // [256][256] bf16
    const float* __restrict__ bias,
    unsigned short* __restrict__ out_bf,     // MODE 0: h
    float* __restrict__ out_f0,              // MODE 1: out
    unsigned short* __restrict__ g2b)        // MODE 1: g2 bf16
{
    __shared__ unsigned short Al[64][GPAD];
    __shared__ unsigned short Bl[256][GPAD];

    const int t = threadIdx.x;
    const int wid = t >> 6;
    const int lane = t & 63;
    const int l15 = lane & 15;
    const int lhi = lane >> 4;
    const int row0 = blockIdx.x * 64;

    f32x4 acc[16];
#pragma unroll
    for (int n = 0; n < 16; ++n) acc[n] = f32x4{0.f, 0.f, 0.f, 0.f};

    for (int kc = 0; kc < 256; kc += 64) {
        __syncthreads();
#pragma unroll
        for (int i = 0; i < 2; ++i) {
            int idx = t + i * 256;
            int r = idx >> 3;
            int c = (idx & 7) * 8;
            int rr = row0 + r;
            if (rr >= NN) rr = NN - 1;
            *reinterpret_cast<uint4*>(&Al[r][c]) =
                *reinterpret_cast<const uint4*>(A + (size_t)rr * 256 + kc + c);
        }
#pragma unroll
        for (int i = 0; i < 8; ++i) {
            int idx = t + i * 256;
            int r = idx >> 3;
            int c = (idx & 7) * 8;
            *reinterpret_cast<uint4*>(&Bl[r][c]) =
                *reinterpret_cast<const uint4*>(BT + (size_t)r * 256 + kc + c);
        }
        __syncthreads();
#pragma unroll
        for (int ks = 0; ks < 64; ks += 32) {
            bf16x8 a = *reinterpret_cast<const bf16x8*>(&Al[wid * 16 + l15][ks + lhi * 8]);
#pragma unroll
            for (int n = 0; n < 16; ++n) {
                bf16x8 b = *reinterpret_cast<const bf16x8*>(&Bl[n * 16 + l15][ks + lhi * 8]);
                acc[n] = __builtin_amdgcn_mfma_f32_16x16x32_bf16(a, b, acc[n], 0, 0, 0);
            }
        }
    }

#pragma unroll
    for (int n = 0; n < 16; ++n) {
        int col = n * 16 + l15;
#pragma unroll
        for (int j = 0; j < 4; ++j) {
            int row = row0 + wid * 16 + lhi * 4 + j;
            if (row < NN) {
                float v = acc[n][j];
                if (MODE == 0) {
                    v += bias[col];
                    v = fmaxf(v, 0.f);
                    out_bf[(size_t)row * 256 + col] = f2bf(v);
                } else {
                    if (col < 128) out_f0[(size_t)row * 128 + col] = v + bias[col];
                    else           g2b[(size_t)row * 128 + (col - 128)] = f2bf(v);
                }
            }
        }
    }
}

// ============================ launch ============================

extern "C" void kernel_launch(void* const* d_in, const int* in_sizes, int n_in,
                              void* d_out, int out_size, void* d_ws, size_t ws_size,
                              hipStream_t stream) {
    const float* x   = (const float*)d_in[0];
    const int*   ei  = (const int*)d_in[1];   // harness stages integers as int32
    const float* W1l = (const float*)d_in[2];
    const float* W1r = (const float*)d_in[3];
    const float* b1  = (const float*)d_in[4];
    const float* W2l = (const float*)d_in[5];
    const float* W2r = (const float*)d_in[6];
    const float* b2  = (const float*)d_in[7];
    float*       out = (float*)d_out;

    // ws layout (4B units): deg_i[N] | rowptr[N] | csr_src[E] | rdeg[N]
    //   | A1 (N*256 bf16; g2b bf16 [N][128] reuses it after L1)
    //   | h (N*256 bf16) | B1T | B2T (32768 units each) | bsum[64 ints]
    const size_t needed =
        ((size_t)NN * 3 + EE + (size_t)NN * 128 * 2 + 65536 + 64) * 4;   // ~55.3 MB
    if (ws_size < needed) return;

    int*            deg_i   = (int*)d_ws;
    int*            rowptr  = deg_i + NN;
    int*            csr_src = rowptr + NN;
    float*          rdeg    = (float*)(csr_src + EE);
    unsigned short* A1      = (unsigned short*)(rdeg + NN);     // [N][256] bf16
    unsigned short* g2b     = A1;                               // [N][128] bf16 (after L1)
    unsigned short* h       = A1 + (size_t)NN * 256;            // [N][256] bf16
    unsigned short* B1T     = h + (size_t)NN * 256;
    unsigned short* B2T     = B1T + 256 * 256;
    int*            bsum    = (int*)(B2T + 256 * 256);

    hipMemsetAsync(deg_i, 0, (size_t)NN * sizeof(int), stream);
    prep_weights<<<256, 256, 0, stream>>>(W1l, W1r, W2l, W2r, B1T, B2T);
    cast_x_kernel<<<(NN * 32 + 255) / 256, 256, 0, stream>>>(x, A1);
    deg_i_kernel<<<(EE + 255) / 256, 256, 0, stream>>>(ei, deg_i);
    scan_phase1<<<SCAN_NBLK, 1024, 0, stream>>>(deg_i, rowptr, bsum);
    scan_phase2<<<1, 64, 0, stream>>>(bsum);
    scan_phase3<<<(NN + 255) / 256, 256, 0, stream>>>(rowptr, bsum);
    rdeg_i_kernel<<<(NN + 255) / 256, 256, 0, stream>>>(deg_i, rdeg);
    slot_kernel<<<(EE + 255) / 256, 256, 0, stream>>>(ei, rowptr, csr_src);

    // layer 1: A1[:,0:128] = mean(bf16 x); h = relu(A1 @ B1T^T + b1) (bf16)
    gather_mean_bf16<<<(NN + 3) / 4, 256, 0, stream>>>(rowptr, csr_src, rdeg, A1);
    mfma_gemm<0><<<(NN + 63) / 64, 256, 0, stream>>>(A1, B1T, b1, h, nullptr, nullptr);

    // layer 2: out = h@W2r + b2 (f32); g2b = bf16(h@W2l) overlaying dead A1
    mfma_gemm<1><<<(NN + 63) / 64, 256, 0, stream>>>(h, B2T, b2, nullptr, out, g2b);

    // out[n] += rdeg[n] * sum g2b[src]
    gather_accum_f32<<<(NN + 3) / 4, 256, 0, stream>>>(rowptr, csr_src, rdeg, g2b, out);
}

// Round 10
// 348.083 us; speedup vs baseline: 8.7098x; 1.1160x over previous
//
#include <hip/hip_runtime.h>

// GraphSAGE 2-layer, mean agg. N=50000, E=800000, F: 128 -> 256 -> 128.
// CSR build -> gather1(mean of bf16 x) -> MFMA L1 -> MFMA L2 -> gather2(bf16 g2, accum).
//   L1: A1=[mean(x)|x] bf16 K-concat,  B1T=[W1l;W1r]^T, epi: +b1, relu -> h bf16
//   L2: A2=h, B2T=[W2r|W2l] N-concat, epi: cols<128 -> out=+b2 (f32),
//                                          cols>=128 -> g2 bf16 (reuses A1 buf)
//   out[n] += rdeg[n] * sum_{src} g2[src]   (linearity of mean)
// NOTE: harness delivers integer inputs as int32 (NOT int64 as in the JAX ref).
constexpr int NN = 50000;
constexpr int EE = 800000;
constexpr int FI = 128;
constexpr int FO = 128;

typedef __attribute__((ext_vector_type(4))) float f32x4;
typedef __attribute__((ext_vector_type(8))) short bf16x8;

__device__ inline unsigned short f2bf(float f) {   // RNE f32 -> bf16
    union { float f; unsigned u; } v; v.f = f;
    unsigned r = v.u + 0x7FFFu + ((v.u >> 16) & 1u);
    return (unsigned short)(r >> 16);
}
__device__ inline float bf2f(unsigned short u) {
    union { unsigned u; float f; } v; v.u = ((unsigned)u) << 16; return v.f;
}

// ============================ CSR build ============================

__global__ void deg_i_kernel(const int* __restrict__ ei, int* __restrict__ deg) {
    int e = blockIdx.x * blockDim.x + threadIdx.x;
    if (e < EE) atomicAdd(&deg[ei[EE + e]], 1);
}

// 3-phase exclusive scan of deg -> rowptr; phase1 also emits rdeg = 1/max(deg,1).
constexpr int SCAN_NBLK = (NN + 1023) / 1024;   // 49

__global__ __launch_bounds__(1024) void scan_phase1(const int* __restrict__ deg,
                                                    int* __restrict__ rowptr,
                                                    int* __restrict__ bsum,
                                                    float* __restrict__ rdeg) {
    __shared__ int wsum[16];
    const int tid = threadIdx.x;
    const int lane = tid & 63;
    const int wid = tid >> 6;
    int i = blockIdx.x * 1024 + tid;
    int v = (i < NN) ? deg[i] : 0;
    if (i < NN) rdeg[i] = 1.0f / fmaxf((float)v, 1.0f);
    int s = v;
#pragma unroll
    for (int off = 1; off < 64; off <<= 1) {
        int t = __shfl_up(s, off, 64);
        if (lane >= off) s += t;
    }
    if (lane == 63) wsum[wid] = s;
    __syncthreads();
    if (wid == 0) {
        int ws = (lane < 16) ? wsum[lane] : 0;
#pragma unroll
        for (int off = 1; off < 16; off <<= 1) {
            int t = __shfl_up(ws, off, 64);
            if (lane >= off) ws += t;
        }
        if (lane < 16) wsum[lane] = ws;
    }
    __syncthreads();
    int woff = (wid > 0) ? wsum[wid - 1] : 0;
    if (i < NN) rowptr[i] = woff + s - v;           // exclusive within block
    if (tid == 0) bsum[blockIdx.x] = wsum[15];      // block total
}

__global__ void scan_phase2(int* __restrict__ bsum) {   // one wave, NBLK<=64
    int lane = threadIdx.x;
    int v = (lane < SCAN_NBLK) ? bsum[lane] : 0;
    int s = v;
#pragma unroll
    for (int off = 1; off < 64; off <<= 1) {
        int t = __shfl_up(s, off, 64);
        if (lane >= off) s += t;
    }
    if (lane < SCAN_NBLK) bsum[lane] = s - v;       // exclusive block offsets
}

__global__ void scan_phase3(int* __restrict__ rowptr, const int* __restrict__ bsum) {
    int i = blockIdx.x * blockDim.x + threadIdx.x;
    if (i < NN) rowptr[i] += bsum[i >> 10];
}

// slot = old rowptr[dst]; after kernel rowptr[n] = end offset of node n.
__global__ void slot_kernel(const int* __restrict__ ei, int* __restrict__ rowptr,
                            int* __restrict__ csr_src) {
    int e = blockIdx.x * blockDim.x + threadIdx.x;
    if (e < EE) {
        int src = ei[e];
        int dst = ei[EE + e];
        int slot = atomicAdd(&rowptr[dst], 1);
        csr_src[slot] = src;
    }
}

// ============================ gathers ============================
// One 64-lane wave per node, bf16 rows (256 B/row), unroll-4 latency chains.

// mean over neighbors of bf16 x (A1 cols [128,256)) -> bf16 A1 cols [0,128).
__global__ __launch_bounds__(256) void gather_mean_bf16(
    const int* __restrict__ rowptr, const int* __restrict__ csr_src,
    const float* __restrict__ rdeg,
    unsigned short* __restrict__ A1)        // [N][256] bf16; reads col128+, writes col<128
{
    int node = blockIdx.x * 4 + (threadIdx.x >> 6);
    if (node >= NN) return;
    int lane = threadIdx.x & 63;
    int f = lane * 2;
    int start = (node == 0) ? 0 : rowptr[node - 1];
    int end = rowptr[node];
    float ax0 = 0.f, ay0 = 0.f, ax1 = 0.f, ay1 = 0.f;
    float ax2 = 0.f, ay2 = 0.f, ax3 = 0.f, ay3 = 0.f;
    int j = start;
    for (; j + 3 < end; j += 4) {
        int s0 = csr_src[j];
        int s1 = csr_src[j + 1];
        int s2 = csr_src[j + 2];
        int s3 = csr_src[j + 3];
        ushort2 v0 = *reinterpret_cast<const ushort2*>(A1 + (size_t)s0 * 256 + 128 + f);
        ushort2 v1 = *reinterpret_cast<const ushort2*>(A1 + (size_t)s1 * 256 + 128 + f);
        ushort2 v2 = *reinterpret_cast<const ushort2*>(A1 + (size_t)s2 * 256 + 128 + f);
        ushort2 v3 = *reinterpret_cast<const ushort2*>(A1 + (size_t)s3 * 256 + 128 + f);
        ax0 += bf2f(v0.x); ay0 += bf2f(v0.y);
        ax1 += bf2f(v1.x); ay1 += bf2f(v1.y);
        ax2 += bf2f(v2.x); ay2 += bf2f(v2.y);
        ax3 += bf2f(v3.x); ay3 += bf2f(v3.y);
    }
    for (; j < end; ++j) {
        int s0 = csr_src[j];
        ushort2 v0 = *reinterpret_cast<const ushort2*>(A1 + (size_t)s0 * 256 + 128 + f);
        ax0 += bf2f(v0.x); ay0 += bf2f(v0.y);
    }
    float s = rdeg[node];
    ushort2 o;
    o.x = f2bf(((ax0 + ax1) + (ax2 + ax3)) * s);
    o.y = f2bf(((ay0 + ay1) + (ay2 + ay3)) * s);
    *reinterpret_cast<ushort2*>(A1 + (size_t)node * 256 + f) = o;
}

// out[node] += rdeg[node] * sum g2b[src]   (g2b bf16 [N][128], out f32)
__global__ __launch_bounds__(256) void gather_accum_f32(
    const int* __restrict__ rowptr, const int* __restrict__ csr_src,
    const float* __restrict__ rdeg, const unsigned short* __restrict__ g2b,
    float* __restrict__ outp)
{
    int node = blockIdx.x * 4 + (threadIdx.x >> 6);
    if (node >= NN) return;
    int lane = threadIdx.x & 63;
    int f = lane * 2;
    int start = (node == 0) ? 0 : rowptr[node - 1];
    int end = rowptr[node];
    float ax0 = 0.f, ay0 = 0.f, ax1 = 0.f, ay1 = 0.f;
    float ax2 = 0.f, ay2 = 0.f, ax3 = 0.f, ay3 = 0.f;
    int j = start;
    for (; j + 3 < end; j += 4) {
        int s0 = csr_src[j];
        int s1 = csr_src[j + 1];
        int s2 = csr_src[j + 2];
        int s3 = csr_src[j + 3];
        ushort2 v0 = *reinterpret_cast<const ushort2*>(g2b + (size_t)s0 * 128 + f);
        ushort2 v1 = *reinterpret_cast<const ushort2*>(g2b + (size_t)s1 * 128 + f);
        ushort2 v2 = *reinterpret_cast<const ushort2*>(g2b + (size_t)s2 * 128 + f);
        ushort2 v3 = *reinterpret_cast<const ushort2*>(g2b + (size_t)s3 * 128 + f);
        ax0 += bf2f(v0.x); ay0 += bf2f(v0.y);
        ax1 += bf2f(v1.x); ay1 += bf2f(v1.y);
        ax2 += bf2f(v2.x); ay2 += bf2f(v2.y);
        ax3 += bf2f(v3.x); ay3 += bf2f(v3.y);
    }
    for (; j < end; ++j) {
        int s0 = csr_src[j];
        ushort2 v0 = *reinterpret_cast<const ushort2*>(g2b + (size_t)s0 * 128 + f);
        ax0 += bf2f(v0.x); ay0 += bf2f(v0.y);
    }
    float s = rdeg[node];
    float* p = outp + (size_t)node * FO + f;
    float2 o = *reinterpret_cast<float2*>(p);
    o.x += ((ax0 + ax1) + (ax2 + ax3)) * s;
    o.y += ((ay0 + ay1) + (ay2 + ay3)) * s;
    *reinterpret_cast<float2*>(p) = o;
}

// ============================ prep kernels ============================

__global__ void cast_x_kernel(const float* __restrict__ x,
                              unsigned short* __restrict__ A1) {
    int i = blockIdx.x * blockDim.x + threadIdx.x;    // N*32 float4s
    if (i >= NN * 32) return;
    int n = i >> 5;
    int c4 = (i & 31) * 4;
    float4 v = *reinterpret_cast<const float4*>(x + (size_t)n * FI + c4);
    ushort4 o;
    o.x = f2bf(v.x); o.y = f2bf(v.y); o.z = f2bf(v.z); o.w = f2bf(v.w);
    *reinterpret_cast<ushort4*>(A1 + (size_t)n * 256 + 128 + c4) = o;
}

// B1T[n][k] = k<128 ? W1l[k][n] : W1r[k-128][n]     (W1* are [128][256])
// B2T[n][k] = n<128 ? W2r[k][n] : W2l[k][n-128]     (W2* are [256][128])
__global__ void prep_weights(const float* __restrict__ W1l, const float* __restrict__ W1r,
                             const float* __restrict__ W2l, const float* __restrict__ W2r,
                             unsigned short* __restrict__ B1T,
                             unsigned short* __restrict__ B2T) {
    int i = blockIdx.x * blockDim.x + threadIdx.x;
    if (i >= 256 * 256) return;
    int n = i >> 8, k = i & 255;
    float v1 = (k < 128) ? W1l[(size_t)k * 256 + n] : W1r[(size_t)(k - 128) * 256 + n];
    B1T[(size_t)n * 256 + k] = f2bf(v1);
    float v2 = (n < 128) ? W2r[(size_t)k * 128 + n] : W2l[(size_t)k * 128 + (n - 128)];
    B2T[(size_t)n * 256 + k] = f2bf(v2);
}

// ============================ MFMA GEMM ============================
// C[N x 256] = A[N x 256] @ B^T[256 x 256], bf16 in, f32 acc.
// 256 thr / 4 waves in a 2x2 wave grid: wave (wr,wc) owns rows wr*32..+32,
// cols wc*128..+128 -> acc[2][8]; per ks: 2 A-frag + 8 B-frag ds_reads for
// 16 MFMA (vs 17:16 before), B frags shared by only 2 waves.
// GPAD=72 shorts (144 B rows): bank = (4r+c) mod 32 -> 2-way max (free, m136).
// MODE 0 (L1): +bias[256], relu, store bf16 h.   MODE 1 (L2): col<128 ->
// out_f0 = acc + bias (f32); col>=128 -> g2b = bf16(acc).
constexpr int GPAD = 72;

template<int MODE>
__global__ __launch_bounds__(256) void mfma_gemm(
    const unsigned short* __restrict__ A,    // [N][256] bf16
    const unsigned short* __restrict__ BT,   // [256][256] bf16
    const float* __restrict__ bias,
    unsigned short* __restrict__ out_bf,     // MODE 0: h
    float* __restrict__ out_f0,              // MODE 1: out
    unsigned short* __restrict__ g2b)        // MODE 1: g2 bf16
{
    __shared__ unsigned short Al[64][GPAD];    // 9.2 KB
    __shared__ unsigned short Bl[256][GPAD];   // 36.9 KB

    const int t = threadIdx.x;
    const int wid = t >> 6;
    const int wr = wid >> 1;            // 0..1: row half
    const int wc = wid & 1;             // 0..1: col half
    const int lane = t & 63;
    const int l15 = lane & 15;
    const int lhi = lane >> 4;
    const int row0 = blockIdx.x * 64;

    f32x4 acc[2][8];
#pragma unroll
    for (int m = 0; m < 2; ++m)
#pragma unroll
        for (int n = 0; n < 8; ++n) acc[m][n] = f32x4{0.f, 0.f, 0.f, 0.f};

    for (int kc = 0; kc < 256; kc += 64) {
        __syncthreads();
#pragma unroll
        for (int i = 0; i < 2; ++i) {
            int idx = t + i * 256;
            int r = idx >> 3;
            int c = (idx & 7) * 8;
            int rr = row0 + r;
            if (rr >= NN) rr = NN - 1;
            *reinterpret_cast<uint4*>(&Al[r][c]) =
                *reinterpret_cast<const uint4*>(A + (size_t)rr * 256 + kc + c);
        }
#pragma unroll
        for (int i = 0; i < 8; ++i) {
            int idx = t + i * 256;
            int r = idx >> 3;
            int c = (idx & 7) * 8;
            *reinterpret_cast<uint4*>(&Bl[r][c]) =
                *reinterpret_cast<const uint4*>(BT + (size_t)r * 256 + kc + c);
        }
        __syncthreads();
#pragma unroll
        for (int ks = 0; ks < 64; ks += 32) {
            bf16x8 a0 = *reinterpret_cast<const bf16x8*>(&Al[wr * 32 + l15][ks + lhi * 8]);
            bf16x8 a1 = *reinterpret_cast<const bf16x8*>(&Al[wr * 32 + 16 + l15][ks + lhi * 8]);
#pragma unroll
            for (int n = 0; n < 8; ++n) {
                bf16x8 b = *reinterpret_cast<const bf16x8*>(
                    &Bl[wc * 128 + n * 16 + l15][ks + lhi * 8]);
                acc[0][n] = __builtin_amdgcn_mfma_f32_16x16x32_bf16(a0, b, acc[0][n], 0, 0, 0);
                acc[1][n] = __builtin_amdgcn_mfma_f32_16x16x32_bf16(a1, b, acc[1][n], 0, 0, 0);
            }
        }
    }

#pragma unroll
    for (int n = 0; n < 8; ++n) {
        int col = wc * 128 + n * 16 + l15;
#pragma unroll
        for (int m = 0; m < 2; ++m) {
#pragma unroll
            for (int j = 0; j < 4; ++j) {
                int row = row0 + wr * 32 + m * 16 + lhi * 4 + j;
                if (row < NN) {
                    float v = acc[m][n][j];
                    if (MODE == 0) {
                        v += bias[col];
                        v = fmaxf(v, 0.f);
                        out_bf[(size_t)row * 256 + col] = f2bf(v);
                    } else {
                        if (col < 128) out_f0[(size_t)row * 128 + col] = v + bias[col];
                        else           g2b[(size_t)row * 128 + (col - 128)] = f2bf(v);
                    }
                }
            }
        }
    }
}

// ============================ launch ============================

extern "C" void kernel_launch(void* const* d_in, const int* in_sizes, int n_in,
                              void* d_out, int out_size, void* d_ws, size_t ws_size,
                              hipStream_t stream) {
    const float* x   = (const float*)d_in[0];
    const int*   ei  = (const int*)d_in[1];   // harness stages integers as int32
    const float* W1l = (const float*)d_in[2];
    const float* W1r = (const float*)d_in[3];
    const float* b1  = (const float*)d_in[4];
    const float* W2l = (const float*)d_in[5];
    const float* W2r = (const float*)d_in[6];
    const float* b2  = (const float*)d_in[7];
    float*       out = (float*)d_out;

    // ws layout (4B units): deg_i[N] | rowptr[N] | csr_src[E] | rdeg[N]
    //   | A1 (N*256 bf16; g2b bf16 [N][128] reuses it after L1)
    //   | h (N*256 bf16) | B1T | B2T (32768 units each) | bsum[64 ints]
    const size_t needed =
        ((size_t)NN * 3 + EE + (size_t)NN * 128 * 2 + 65536 + 64) * 4;   // ~55.3 MB
    if (ws_size < needed) return;

    int*            deg_i   = (int*)d_ws;
    int*            rowptr  = deg_i + NN;
    int*            csr_src = rowptr + NN;
    float*          rdeg    = (float*)(csr_src + EE);
    unsigned short* A1      = (unsigned short*)(rdeg + NN);     // [N][256] bf16
    unsigned short* g2b     = A1;                               // [N][128] bf16 (after L1)
    unsigned short* h       = A1 + (size_t)NN * 256;            // [N][256] bf16
    unsigned short* B1T     = h + (size_t)NN * 256;
    unsigned short* B2T     = B1T + 256 * 256;
    int*            bsum    = (int*)(B2T + 256 * 256);

    hipMemsetAsync(deg_i, 0, (size_t)NN * sizeof(int), stream);
    prep_weights<<<256, 256, 0, stream>>>(W1l, W1r, W2l, W2r, B1T, B2T);
    cast_x_kernel<<<(NN * 32 + 255) / 256, 256, 0, stream>>>(x, A1);
    deg_i_kernel<<<(EE + 255) / 256, 256, 0, stream>>>(ei, deg_i);
    scan_phase1<<<SCAN_NBLK, 1024, 0, stream>>>(deg_i, rowptr, bsum, rdeg);
    scan_phase2<<<1, 64, 0, stream>>>(bsum);
    scan_phase3<<<(NN + 255) / 256, 256, 0, stream>>>(rowptr, bsum);
    slot_kernel<<<(EE + 255) / 256, 256, 0, stream>>>(ei, rowptr, csr_src);

    // layer 1: A1[:,0:128] = mean(bf16 x); h = relu(A1 @ B1T^T + b1) (bf16)
    gather_mean_bf16<<<(NN + 3) / 4, 256, 0, stream>>>(rowptr, csr_src, rdeg, A1);
    mfma_gemm<0><<<(NN + 63) / 64, 256, 0, stream>>>(A1, B1T, b1, h, nullptr, nullptr);

    // layer 2: out = h@W2r + b2 (f32); g2b = bf16(h@W2l) overlaying dead A1
    mfma_gemm<1><<<(NN + 63) / 64, 256, 0, stream>>>(h, B2T, b2, nullptr, out, g2b);

    // out[n] += rdeg[n] * sum g2b[src]
    gather_accum_f32<<<(NN + 3) / 4, 256, 0, stream>>>(rowptr, csr_src, rdeg, g2b, out);
}

// Round 11
// 328.269 us; speedup vs baseline: 9.2355x; 1.0604x over previous
//
#include <hip/hip_runtime.h>

// GraphSAGE 2-layer, mean agg. N=50000, E=800000, F: 128 -> 256 -> 128.
// CSR build (padded line-per-counter atomics) -> gather1 -> MFMA L1 -> MFMA L2
// -> gather2(accum).  Layer-2 scatter replaced by gather via linearity of mean.
// NOTE: harness delivers integer inputs as int32 (NOT int64 as in the JAX ref).
constexpr int NN = 50000;
constexpr int EE = 800000;
constexpr int FI = 128;
constexpr int FO = 128;

typedef __attribute__((ext_vector_type(4))) float f32x4;
typedef __attribute__((ext_vector_type(8))) short bf16x8;

__device__ inline unsigned short f2bf(float f) {   // RNE f32 -> bf16
    union { float f; unsigned u; } v; v.f = f;
    unsigned r = v.u + 0x7FFFu + ((v.u >> 16) & 1u);
    return (unsigned short)(r >> 16);
}
__device__ inline float bf2f(unsigned short u) {
    union { unsigned u; float f; } v; v.u = ((unsigned)u) << 16; return v.f;
}

// ============================ CSR build ============================
// cnt is PADDED: one counter per 64B line (cnt[n*16]) -> no same-line
// serialization across distinct dst at the atomic point.

__global__ void deg_i_kernel(const int* __restrict__ ei, int* __restrict__ cnt) {
    int e = blockIdx.x * blockDim.x + threadIdx.x;
    if (e < EE) atomicAdd(&cnt[ei[EE + e] << 4], 1);
}

// 3-phase exclusive scan of cnt -> rowptr[0..NN); phase1 also emits rdeg.
constexpr int SCAN_NBLK = (NN + 1023) / 1024;   // 49

__global__ __launch_bounds__(1024) void scan_phase1(const int* __restrict__ cnt,
                                                    int* __restrict__ rowptr,
                                                    int* __restrict__ bsum,
                                                    float* __restrict__ rdeg) {
    __shared__ int wsum[16];
    const int tid = threadIdx.x;
    const int lane = tid & 63;
    const int wid = tid >> 6;
    int i = blockIdx.x * 1024 + tid;
    int v = (i < NN) ? cnt[i << 4] : 0;
    if (i < NN) rdeg[i] = 1.0f / fmaxf((float)v, 1.0f);
    int s = v;
#pragma unroll
    for (int off = 1; off < 64; off <<= 1) {
        int t = __shfl_up(s, off, 64);
        if (lane >= off) s += t;
    }
    if (lane == 63) wsum[wid] = s;
    __syncthreads();
    if (wid == 0) {
        int ws = (lane < 16) ? wsum[lane] : 0;
#pragma unroll
        for (int off = 1; off < 16; off <<= 1) {
            int t = __shfl_up(ws, off, 64);
            if (lane >= off) ws += t;
        }
        if (lane < 16) wsum[lane] = ws;
    }
    __syncthreads();
    int woff = (wid > 0) ? wsum[wid - 1] : 0;
    if (i < NN) rowptr[i] = woff + s - v;           // exclusive within block
    if (tid == 0) bsum[blockIdx.x] = wsum[15];      // block total
}

__global__ void scan_phase2(int* __restrict__ bsum) {   // one wave, NBLK<=64
    int lane = threadIdx.x;
    int v = (lane < SCAN_NBLK) ? bsum[lane] : 0;
    int s = v;
#pragma unroll
    for (int off = 1; off < 64; off <<= 1) {
        int t = __shfl_up(s, off, 64);
        if (lane >= off) s += t;
    }
    if (lane < SCAN_NBLK) bsum[lane] = s - v;       // exclusive block offsets
}

__global__ void scan_phase3(int* __restrict__ rowptr, const int* __restrict__ bsum) {
    int i = blockIdx.x * blockDim.x + threadIdx.x;
    if (i < NN) rowptr[i] += bsum[i >> 10];
    else if (i == NN) rowptr[NN] = EE;              // sentinel end
}

// Count-DOWN slot assign reusing cnt (holds deg): slot = rowptr[dst]+old-1.
// rowptr stays intact (read-only exclusive starts; gathers use [n], [n+1]).
__global__ void slot_kernel(const int* __restrict__ ei,
                            const int* __restrict__ rowptr,
                            int* __restrict__ cnt,
                            int* __restrict__ csr_src) {
    int e = blockIdx.x * blockDim.x + threadIdx.x;
    if (e < EE) {
        int src = ei[e];
        int dst = ei[EE + e];
        int old = atomicSub(&cnt[dst << 4], 1);
        csr_src[rowptr[dst] + old - 1] = src;
    }
}

// ============================ gathers ============================
// One 64-lane wave per node, bf16 rows, masked 8-deep load batches
// (kills the serial tail; avg degree 16 = 2 batches).

// mean over neighbors of bf16 x (A1 cols [128,256)) -> bf16 A1 cols [0,128).
__global__ __launch_bounds__(256) void gather_mean_bf16(
    const int* __restrict__ rowptr, const int* __restrict__ csr_src,
    const float* __restrict__ rdeg,
    unsigned short* __restrict__ A1)        // [N][256] bf16
{
    int node = blockIdx.x * 4 + (threadIdx.x >> 6);
    if (node >= NN) return;
    int lane = threadIdx.x & 63;
    int f = lane * 2;
    int start = rowptr[node];
    int end = rowptr[node + 1];
    float ax[8], ay[8];
#pragma unroll
    for (int u = 0; u < 8; ++u) { ax[u] = 0.f; ay[u] = 0.f; }
    for (int j = start; j < end; j += 8) {
        int si[8];
        float w[8];
#pragma unroll
        for (int u = 0; u < 8; ++u) {
            int idx = j + u;
            si[u] = csr_src[idx < end ? idx : start];   // safe dup (line-hot)
            w[u] = (idx < end) ? 1.f : 0.f;
        }
        ushort2 v[8];
#pragma unroll
        for (int u = 0; u < 8; ++u)
            v[u] = *reinterpret_cast<const ushort2*>(A1 + (size_t)si[u] * 256 + 128 + f);
#pragma unroll
        for (int u = 0; u < 8; ++u) {
            ax[u] = fmaf(w[u], bf2f(v[u].x), ax[u]);
            ay[u] = fmaf(w[u], bf2f(v[u].y), ay[u]);
        }
    }
    float s = rdeg[node];
    float sx = ((ax[0] + ax[1]) + (ax[2] + ax[3])) + ((ax[4] + ax[5]) + (ax[6] + ax[7]));
    float sy = ((ay[0] + ay[1]) + (ay[2] + ay[3])) + ((ay[4] + ay[5]) + (ay[6] + ay[7]));
    ushort2 o;
    o.x = f2bf(sx * s);
    o.y = f2bf(sy * s);
    *reinterpret_cast<ushort2*>(A1 + (size_t)node * 256 + f) = o;
}

// out[node] += rdeg[node] * sum g2b[src]   (g2b bf16 [N][128], out f32)
__global__ __launch_bounds__(256) void gather_accum_f32(
    const int* __restrict__ rowptr, const int* __restrict__ csr_src,
    const float* __restrict__ rdeg, const unsigned short* __restrict__ g2b,
    float* __restrict__ outp)
{
    int node = blockIdx.x * 4 + (threadIdx.x >> 6);
    if (node >= NN) return;
    int lane = threadIdx.x & 63;
    int f = lane * 2;
    int start = rowptr[node];
    int end = rowptr[node + 1];
    float ax[8], ay[8];
#pragma unroll
    for (int u = 0; u < 8; ++u) { ax[u] = 0.f; ay[u] = 0.f; }
    for (int j = start; j < end; j += 8) {
        int si[8];
        float w[8];
#pragma unroll
        for (int u = 0; u < 8; ++u) {
            int idx = j + u;
            si[u] = csr_src[idx < end ? idx : start];
            w[u] = (idx < end) ? 1.f : 0.f;
        }
        ushort2 v[8];
#pragma unroll
        for (int u = 0; u < 8; ++u)
            v[u] = *reinterpret_cast<const ushort2*>(g2b + (size_t)si[u] * 128 + f);
#pragma unroll
        for (int u = 0; u < 8; ++u) {
            ax[u] = fmaf(w[u], bf2f(v[u].x), ax[u]);
            ay[u] = fmaf(w[u], bf2f(v[u].y), ay[u]);
        }
    }
    float s = rdeg[node];
    float sx = ((ax[0] + ax[1]) + (ax[2] + ax[3])) + ((ax[4] + ax[5]) + (ax[6] + ax[7]));
    float sy = ((ay[0] + ay[1]) + (ay[2] + ay[3])) + ((ay[4] + ay[5]) + (ay[6] + ay[7]));
    float* p = outp + (size_t)node * FO + f;
    float2 o = *reinterpret_cast<float2*>(p);
    o.x += sx * s;
    o.y += sy * s;
    *reinterpret_cast<float2*>(p) = o;
}

// ============================ prep kernels ============================

__global__ void cast_x_kernel(const float* __restrict__ x,
                              unsigned short* __restrict__ A1) {
    int i = blockIdx.x * blockDim.x + threadIdx.x;    // N*32 float4s
    if (i >= NN * 32) return;
    int n = i >> 5;
    int c4 = (i & 31) * 4;
    float4 v = *reinterpret_cast<const float4*>(x + (size_t)n * FI + c4);
    ushort4 o;
    o.x = f2bf(v.x); o.y = f2bf(v.y); o.z = f2bf(v.z); o.w = f2bf(v.w);
    *reinterpret_cast<ushort4*>(A1 + (size_t)n * 256 + 128 + c4) = o;
}

// B1T[n][k] = k<128 ? W1l[k][n] : W1r[k-128][n]     (W1* are [128][256])
// B2T[n][k] = n<128 ? W2r[k][n] : W2l[k][n-128]     (W2* are [256][128])
__global__ void prep_weights(const float* __restrict__ W1l, const float* __restrict__ W1r,
                             const float* __restrict__ W2l, const float* __restrict__ W2r,
                             unsigned short* __restrict__ B1T,
                             unsigned short* __restrict__ B2T) {
    int i = blockIdx.x * blockDim.x + threadIdx.x;
    if (i >= 256 * 256) return;
    int n = i >> 8, k = i & 255;
    float v1 = (k < 128) ? W1l[(size_t)k * 256 + n] : W1r[(size_t)(k - 128) * 256 + n];
    B1T[(size_t)n * 256 + k] = f2bf(v1);
    float v2 = (n < 128) ? W2r[(size_t)k * 128 + n] : W2l[(size_t)k * 128 + (n - 128)];
    B2T[(size_t)n * 256 + k] = f2bf(v2);
}

// ============================ MFMA GEMM ============================
// C[N x 256] = A[N x 256] @ B^T[256 x 256], bf16 in, f32 acc. (R10 2x2 wave grid)
constexpr int GPAD = 72;

template<int MODE>
__global__ __launch_bounds__(256) void mfma_gemm(
    const unsigned short* __restrict__ A,    // [N][256] bf16
    const unsigned short* __restrict__ BT,   // [256][256] bf16
    const float* __restrict__ bias,
    unsigned short* __restrict__ out_bf,     // MODE 0: h
    float* __restrict__ out_f0,              // MODE 1: out
    unsigned short* __restrict__ g2b)        // MODE 1: g2 bf16
{
    __shared__ unsigned short Al[64][GPAD];    // 9.2 KB
    __shared__ unsigned short Bl[256][GPAD];   // 36.9 KB

    const int t = threadIdx.x;
    const int wid = t >> 6;
    const int wr = wid >> 1;
    const int wc = wid & 1;
    const int lane = t & 63;
    const int l15 = lane & 15;
    const int lhi = lane >> 4;
    const int row0 = blockIdx.x * 64;

    f32x4 acc[2][8];
#pragma unroll
    for (int m = 0; m < 2; ++m)
#pragma unroll
        for (int n = 0; n < 8; ++n) acc[m][n] = f32x4{0.f, 0.f, 0.f, 0.f};

    for (int kc = 0; kc < 256; kc += 64) {
        __syncthreads();
#pragma unroll
        for (int i = 0; i < 2; ++i) {
            int idx = t + i * 256;
            int r = idx >> 3;
            int c = (idx & 7) * 8;
            int rr = row0 + r;
            if (rr >= NN) rr = NN - 1;
            *reinterpret_cast<uint4*>(&Al[r][c]) =
                *reinterpret_cast<const uint4*>(A + (size_t)rr * 256 + kc + c);
        }
#pragma unroll
        for (int i = 0; i < 8; ++i) {
            int idx = t + i * 256;
            int r = idx >> 3;
            int c = (idx & 7) * 8;
            *reinterpret_cast<uint4*>(&Bl[r][c]) =
                *reinterpret_cast<const uint4*>(BT + (size_t)r * 256 + kc + c);
        }
        __syncthreads();
#pragma unroll
        for (int ks = 0; ks < 64; ks += 32) {
            bf16x8 a0 = *reinterpret_cast<const bf16x8*>(&Al[wr * 32 + l15][ks + lhi * 8]);
            bf16x8 a1 = *reinterpret_cast<const bf16x8*>(&Al[wr * 32 + 16 + l15][ks + lhi * 8]);
#pragma unroll
            for (int n = 0; n < 8; ++n) {
                bf16x8 b = *reinterpret_cast<const bf16x8*>(
                    &Bl[wc * 128 + n * 16 + l15][ks + lhi * 8]);
                acc[0][n] = __builtin_amdgcn_mfma_f32_16x16x32_bf16(a0, b, acc[0][n], 0, 0, 0);
                acc[1][n] = __builtin_amdgcn_mfma_f32_16x16x32_bf16(a1, b, acc[1][n], 0, 0, 0);
            }
        }
    }

#pragma unroll
    for (int n = 0; n < 8; ++n) {
        int col = wc * 128 + n * 16 + l15;
#pragma unroll
        for (int m = 0; m < 2; ++m) {
#pragma unroll
            for (int j = 0; j < 4; ++j) {
                int row = row0 + wr * 32 + m * 16 + lhi * 4 + j;
                if (row < NN) {
                    float v = acc[m][n][j];
                    if (MODE == 0) {
                        v += bias[col];
                        v = fmaxf(v, 0.f);
                        out_bf[(size_t)row * 256 + col] = f2bf(v);
                    } else {
                        if (col < 128) out_f0[(size_t)row * 128 + col] = v + bias[col];
                        else           g2b[(size_t)row * 128 + (col - 128)] = f2bf(v);
                    }
                }
            }
        }
    }
}

// ============================ launch ============================

extern "C" void kernel_launch(void* const* d_in, const int* in_sizes, int n_in,
                              void* d_out, int out_size, void* d_ws, size_t ws_size,
                              hipStream_t stream) {
    const float* x   = (const float*)d_in[0];
    const int*   ei  = (const int*)d_in[1];   // harness stages integers as int32
    const float* W1l = (const float*)d_in[2];
    const float* W1r = (const float*)d_in[3];
    const float* b1  = (const float*)d_in[4];
    const float* W2l = (const float*)d_in[5];
    const float* W2r = (const float*)d_in[6];
    const float* b2  = (const float*)d_in[7];
    float*       out = (float*)d_out;

    // ws layout (4B units): cnt[N*16 padded] | rowptr[N+16] | csr_src[E] | rdeg[N]
    //   | A1 (N*256 bf16; g2b reuses after L1) | h (N*256 bf16) | B1T | B2T | bsum
    const size_t needed =
        ((size_t)NN * 16 + (NN + 16) + EE + NN
         + (size_t)NN * 128 * 2 + 65536 + 64) * 4;   // ~58.3 MB (< proven 80.6)
    if (ws_size < needed) return;

    int*            cnt     = (int*)d_ws;                       // padded counters
    int*            rowptr  = cnt + (size_t)NN * 16;            // [N+1] exclusive
    int*            csr_src = rowptr + (NN + 16);
    float*          rdeg    = (float*)(csr_src + EE);
    unsigned short* A1      = (unsigned short*)(rdeg + NN);     // [N][256] bf16
    unsigned short* g2b     = A1;                               // [N][128] bf16 (after L1)
    unsigned short* h       = A1 + (size_t)NN * 256;            // [N][256] bf16
    unsigned short* B1T     = h + (size_t)NN * 256;
    unsigned short* B2T     = B1T + 256 * 256;
    int*            bsum    = (int*)(B2T + 256 * 256);

    hipMemsetAsync(cnt, 0, (size_t)NN * 16 * sizeof(int), stream);
    prep_weights<<<256, 256, 0, stream>>>(W1l, W1r, W2l, W2r, B1T, B2T);
    cast_x_kernel<<<(NN * 32 + 255) / 256, 256, 0, stream>>>(x, A1);
    deg_i_kernel<<<(EE + 255) / 256, 256, 0, stream>>>(ei, cnt);
    scan_phase1<<<SCAN_NBLK, 1024, 0, stream>>>(cnt, rowptr, bsum, rdeg);
    scan_phase2<<<1, 64, 0, stream>>>(bsum);
    scan_phase3<<<(NN + 256) / 256, 256, 0, stream>>>(rowptr, bsum);
    slot_kernel<<<(EE + 255) / 256, 256, 0, stream>>>(ei, rowptr, cnt, csr_src);

    // layer 1: A1[:,0:128] = mean(bf16 x); h = relu(A1 @ B1T^T + b1) (bf16)
    gather_mean_bf16<<<(NN + 3) / 4, 256, 0, stream>>>(rowptr, csr_src, rdeg, A1);
    mfma_gemm<0><<<(NN + 63) / 64, 256, 0, stream>>>(A1, B1T, b1, h, nullptr, nullptr);

    // layer 2: out = h@W2r + b2 (f32); g2b = bf16(h@W2l) overlaying dead A1
    mfma_gemm<1><<<(NN + 63) / 64, 256, 0, stream>>>(h, B2T, b2, nullptr, out, g2b);

    // out[n] += rdeg[n] * sum g2b[src]
    gather_accum_f32<<<(NN + 3) / 4, 256, 0, stream>>>(rowptr, csr_src, rdeg, g2b, out);
}